// Round 3
// baseline (35.638 us; speedup 1.0000x reference)
//
#include <hip/hip_runtime.h>

#define IN_DIM 2048
#define OUT_DIM 2048
#define LVAL 256

// Second launch_bounds arg = min waves per SIMD (EU). 4 -> VGPR budget 128,
// so the 24 up-front 16B loads can all stay in flight (96 VGPRs of payload).
__global__ __launch_bounds__(256, 4) void ulc_kernel(
    const float* __restrict__ input_r, const float* __restrict__ input_i,
    const float* __restrict__ src_r,   const float* __restrict__ src_i,
    const float* __restrict__ rng,
    const int* __restrict__ i1_frwr, const int* __restrict__ i0_frwr,
    const int* __restrict__ i1_frwi, const int* __restrict__ i0_frwi,
    const int* __restrict__ i1_fiwr, const int* __restrict__ i0_fiwr,
    const int* __restrict__ i1_fiwi, const int* __restrict__ i0_fiwi,
    float* __restrict__ out)
{
    __shared__ float rng_s[LVAL];
    __shared__ int redA[4], redB[4];
    const int tid = threadIdx.x;
    rng_s[tid] = rng[tid];            // 256 threads, 256 entries
    __syncthreads();

    const int o = blockIdx.x;
    const size_t base = (size_t)o * IN_DIM + tid * 8;   // 8 columns per thread
    const int cx = tid * 8;

    // ---- issue ALL loads up front (24 x 16B independent) ----
    const float4 sr_0 = *(const float4*)(src_r + base);
    const float4 sr_1 = *(const float4*)(src_r + base + 4);
    const float4 si_0 = *(const float4*)(src_i + base);
    const float4 si_1 = *(const float4*)(src_i + base + 4);
    const float4 xr_0 = *(const float4*)(input_r + cx);
    const float4 xr_1 = *(const float4*)(input_r + cx + 4);
    const float4 xi_0 = *(const float4*)(input_i + cx);
    const float4 xi_1 = *(const float4*)(input_i + cx + 4);
    const int4 a1_0 = *(const int4*)(i1_frwr + base);
    const int4 a1_1 = *(const int4*)(i1_frwr + base + 4);
    const int4 a0_0 = *(const int4*)(i0_frwr + base);
    const int4 a0_1 = *(const int4*)(i0_frwr + base + 4);
    const int4 b1_0 = *(const int4*)(i1_frwi + base);
    const int4 b1_1 = *(const int4*)(i1_frwi + base + 4);
    const int4 b0_0 = *(const int4*)(i0_frwi + base);
    const int4 b0_1 = *(const int4*)(i0_frwi + base + 4);
    const int4 c1_0 = *(const int4*)(i1_fiwr + base);
    const int4 c1_1 = *(const int4*)(i1_fiwr + base + 4);
    const int4 c0_0 = *(const int4*)(i0_fiwr + base);
    const int4 c0_1 = *(const int4*)(i0_fiwr + base + 4);
    const int4 d1_0 = *(const int4*)(i1_fiwi + base);
    const int4 d1_1 = *(const int4*)(i1_fiwi + base + 4);
    const int4 d0_0 = *(const int4*)(i0_fiwi + base);
    const int4 d0_1 = *(const int4*)(i0_fiwi + base + 4);

    int accA = 0, accB = 0;

    // bit = x ? (src > rng[idx1]) : 1 - (src > rng[idx0])
    //     = (src > rng[x ? idx1 : idx0]) == x           (select address, 1 gather)
    // fiwi kernel's x is (1 - xi): contrib = (cmp != xi)
    #define ELEM(k, e)                                                           \
    {                                                                            \
        const float sr = sr_##k.e, si = si_##k.e;                                \
        const bool xr = xr_##k.e > 0.5f;                                         \
        const bool xi = xi_##k.e > 0.5f;                                         \
        const int ia = (xr ? a1_##k.e : a0_##k.e) & 255;                         \
        const int ib = (xr ? b1_##k.e : b0_##k.e) & 255;                         \
        const int ic = (xi ? c1_##k.e : c0_##k.e) & 255;                         \
        const int id = (xi ? d0_##k.e : d1_##k.e) & 255;                         \
        const bool cA = sr > rng_s[ia];                                          \
        const bool cB = si > rng_s[ib];                                          \
        const bool cC = sr > rng_s[ic];                                          \
        const bool cD = si > rng_s[id];                                          \
        accA += (int)(cA == xr) + (int)(cD != xi);                               \
        accB += (int)(cB == xr) + (int)(cC == xi);                               \
    }
    ELEM(0, x) ELEM(0, y) ELEM(0, z) ELEM(0, w)
    ELEM(1, x) ELEM(1, y) ELEM(1, z) ELEM(1, w)
    #undef ELEM

    // wave (64-lane) reduction
    #pragma unroll
    for (int off = 32; off > 0; off >>= 1) {
        accA += __shfl_down(accA, off);
        accB += __shfl_down(accB, off);
    }
    const int wid = tid >> 6;
    if ((tid & 63) == 0) { redA[wid] = accA; redB[wid] = accB; }
    __syncthreads();
    if (tid == 0) {
        const int sA = redA[0] + redA[1] + redA[2] + redA[3];
        const int sB = redB[0] + redB[1] + redB[2] + redB[3];
        out[o]           = (sA >= 2048) ? 1.0f : 0.0f;  // acc - 2047.5 > 0
        out[OUT_DIM + o] = (sB >= 2048) ? 1.0f : 0.0f;
    }
}

extern "C" void kernel_launch(void* const* d_in, const int* in_sizes, int n_in,
                              void* d_out, int out_size, void* d_ws, size_t ws_size,
                              hipStream_t stream) {
    const float* input_r = (const float*)d_in[0];
    const float* input_i = (const float*)d_in[1];
    const float* src_r   = (const float*)d_in[2];
    const float* src_i   = (const float*)d_in[3];
    const float* rng     = (const float*)d_in[4];
    const int* i1_frwr = (const int*)d_in[5];
    const int* i0_frwr = (const int*)d_in[6];
    const int* i1_frwi = (const int*)d_in[7];
    const int* i0_frwi = (const int*)d_in[8];
    const int* i1_fiwr = (const int*)d_in[9];
    const int* i0_fiwr = (const int*)d_in[10];
    const int* i1_fiwi = (const int*)d_in[11];
    const int* i0_fiwi = (const int*)d_in[12];
    float* out = (float*)d_out;

    ulc_kernel<<<dim3(OUT_DIM), dim3(256), 0, stream>>>(
        input_r, input_i, src_r, src_i, rng,
        i1_frwr, i0_frwr, i1_frwi, i0_frwi,
        i1_fiwr, i0_fiwr, i1_fiwi, i0_fiwi,
        out);
}

// Round 4
// 30.967 us; speedup vs baseline: 1.1508x; 1.1508x over previous
//
#include <hip/hip_runtime.h>

#define IN_DIM 2048
#define OUT_DIM 2048
#define TILE 512
#define NT 4            // IN_DIM / TILE

typedef const __attribute__((address_space(1))) unsigned int* gp_t;
typedef __attribute__((address_space(3))) unsigned int* lp_t;

// LDS tile row order: m0 src_r, m1 src_i, m2 a1, m3 a0, m4 b1, m5 b0,
//                     m6 c1, m7 c0, m8 d1, m9 d0   (segment s: m=s>>1, half=s&1)
__global__ __launch_bounds__(256) void ulc_kernel(
    const float* __restrict__ input_r, const float* __restrict__ input_i,
    const float* __restrict__ src_r,   const float* __restrict__ src_i,
    const float* __restrict__ rng,
    const int* __restrict__ i1_frwr, const int* __restrict__ i0_frwr,
    const int* __restrict__ i1_frwi, const int* __restrict__ i0_frwi,
    const int* __restrict__ i1_fiwr, const int* __restrict__ i0_fiwr,
    const int* __restrict__ i1_fiwi, const int* __restrict__ i0_fiwi,
    float* __restrict__ out)
{
    __shared__ unsigned int tile[2][10 * TILE];   // 2 x 20KB
    __shared__ float rng_s[256];
    __shared__ int redA[4], redB[4];

    const int tid  = threadIdx.x;
    const int wid  = tid >> 6;
    const int lane = tid & 63;
    const int o    = blockIdx.x;
    const size_t row = (size_t)o * IN_DIM;

    rng_s[tid] = rng[tid];                        // 1 vmem + ds_write

    // ---- hoist x-vector loads (8 vmem), consume into bools in prologue ----
    float2 xr2[NT], xi2[NT];
    #pragma unroll
    for (int t = 0; t < NT; ++t) {
        xr2[t] = *(const float2*)(input_r + t * TILE + tid * 2);
        xi2[t] = *(const float2*)(input_i + t * TILE + tid * 2);
    }
    bool xrb[2 * NT], xib[2 * NT];
    #pragma unroll
    for (int t = 0; t < NT; ++t) {
        xrb[2*t] = xr2[t].x > 0.5f;  xrb[2*t+1] = xr2[t].y > 0.5f;
        xib[2*t] = xi2[t].x > 0.5f;  xib[2*t+1] = xi2[t].y > 0.5f;
    }
    __builtin_amdgcn_sched_barrier(0);

    // async stage: segment s (0..19), 64 lanes x 16B = 1KB each, LDS dest linear
    #define SEG(s, P, t, b)                                                         \
        __builtin_amdgcn_global_load_lds(                                           \
            (gp_t)((const unsigned int*)(P) + row + (size_t)(t) * TILE              \
                   + ((s) & 1) * 256 + lane * 4),                                   \
            (lp_t)(&tile[(b)][(s) * 256]), 16, 0, 0);

    #define STAGE(t, b)                                                                          \
        if (wid == 0)      { SEG(0,src_r,t,b)   SEG(1,src_r,t,b)   SEG(2,src_i,t,b)              \
                             SEG(3,src_i,t,b)   SEG(4,i1_frwr,t,b) }                             \
        else if (wid == 1) { SEG(5,i1_frwr,t,b) SEG(6,i0_frwr,t,b) SEG(7,i0_frwr,t,b)            \
                             SEG(8,i1_frwi,t,b) SEG(9,i1_frwi,t,b) }                             \
        else if (wid == 2) { SEG(10,i0_frwi,t,b) SEG(11,i0_frwi,t,b) SEG(12,i1_fiwr,t,b)         \
                             SEG(13,i1_fiwr,t,b) SEG(14,i0_fiwr,t,b) }                           \
        else               { SEG(15,i0_fiwr,t,b) SEG(16,i1_fiwi,t,b) SEG(17,i1_fiwi,t,b)         \
                             SEG(18,i0_fiwi,t,b) SEG(19,i0_fiwi,t,b) }

    int accA = 0, accB = 0;

    STAGE(0, 0)                                   // 5 vmem per wave

    #pragma unroll
    for (int t = 0; t < NT; ++t) {
        if (t + 1 < NT) { STAGE(t + 1, (t + 1) & 1) }     // prefetch (async, 5/wave)
        // drain current tile's 5 (plus any older prologue vmem), keep prefetch in flight
        if (t + 1 < NT) asm volatile("s_waitcnt vmcnt(5) lgkmcnt(0)" ::: "memory");
        else            asm volatile("s_waitcnt vmcnt(0) lgkmcnt(0)" ::: "memory");
        __builtin_amdgcn_s_barrier();
        __builtin_amdgcn_sched_barrier(0);

        const unsigned int* tl = &tile[t & 1][0];
        const int j0 = tid * 2;
        #pragma unroll
        for (int q = 0; q < 2; ++q) {
            const int j = j0 + q;
            const bool xr = xrb[2*t + q], xi = xib[2*t + q];
            const float sr = __uint_as_float(tl[0 * TILE + j]);
            const float si = __uint_as_float(tl[1 * TILE + j]);
            const int ia = tl[(xr ? 2 : 3) * TILE + j] & 255;
            const int ib = tl[(xr ? 4 : 5) * TILE + j] & 255;
            const int ic = tl[(xi ? 6 : 7) * TILE + j] & 255;
            const int id = tl[(xi ? 9 : 8) * TILE + j] & 255;  // x=1-xi: xi? d0 : d1
            const bool cA = sr > rng_s[ia];
            const bool cB = si > rng_s[ib];
            const bool cC = sr > rng_s[ic];
            const bool cD = si > rng_s[id];
            accA += (int)(cA == xr) + (int)(cD != xi);
            accB += (int)(cB == xr) + (int)(cC == xi);
        }
        __builtin_amdgcn_sched_barrier(0);
        __builtin_amdgcn_s_barrier();             // all waves done reading buf before overwrite
    }

    // ---- wave (64-lane) reduction, then cross-wave via LDS ----
    #pragma unroll
    for (int off = 32; off > 0; off >>= 1) {
        accA += __shfl_down(accA, off);
        accB += __shfl_down(accB, off);
    }
    if ((tid & 63) == 0) { redA[wid] = accA; redB[wid] = accB; }
    __syncthreads();
    if (tid == 0) {
        const int sA = redA[0] + redA[1] + redA[2] + redA[3];
        const int sB = redB[0] + redB[1] + redB[2] + redB[3];
        out[o]           = (sA >= 2048) ? 1.0f : 0.0f;   // acc - 2047.5 > 0
        out[OUT_DIM + o] = (sB >= 2048) ? 1.0f : 0.0f;
    }
}

extern "C" void kernel_launch(void* const* d_in, const int* in_sizes, int n_in,
                              void* d_out, int out_size, void* d_ws, size_t ws_size,
                              hipStream_t stream) {
    const float* input_r = (const float*)d_in[0];
    const float* input_i = (const float*)d_in[1];
    const float* src_r   = (const float*)d_in[2];
    const float* src_i   = (const float*)d_in[3];
    const float* rng     = (const float*)d_in[4];
    const int* i1_frwr = (const int*)d_in[5];
    const int* i0_frwr = (const int*)d_in[6];
    const int* i1_frwi = (const int*)d_in[7];
    const int* i0_frwi = (const int*)d_in[8];
    const int* i1_fiwr = (const int*)d_in[9];
    const int* i0_fiwr = (const int*)d_in[10];
    const int* i1_fiwi = (const int*)d_in[11];
    const int* i0_fiwi = (const int*)d_in[12];
    float* out = (float*)d_out;

    ulc_kernel<<<dim3(OUT_DIM), dim3(256), 0, stream>>>(
        input_r, input_i, src_r, src_i, rng,
        i1_frwr, i0_frwr, i1_frwi, i0_frwi,
        i1_fiwr, i0_fiwr, i1_fiwi, i0_fiwi,
        out);
}

// Round 5
// 30.324 us; speedup vs baseline: 1.1752x; 1.0212x over previous
//
#include <hip/hip_runtime.h>

#define IN_DIM 2048
#define OUT_DIM 2048

typedef __attribute__((ext_vector_type(4))) int int4v;

// Forced-issue 16B load: saddr form, 32-bit voffset. asm volatile keeps all
// 20 loads in one issue batch -- the compiler cannot sink/serialize them.
#define GLOAD(dst, ptr, voff)                                   \
    asm volatile("global_load_dwordx4 %0, %1, %2"               \
                 : "=v"(dst)                                    \
                 : "v"(voff), "s"(ptr)                          \
                 : "memory")

__global__ __launch_bounds__(256, 4) void ulc_kernel(
    const float* __restrict__ input_r, const float* __restrict__ input_i,
    const float* __restrict__ src_r,   const float* __restrict__ src_i,
    const float* __restrict__ rng,
    const int* __restrict__ i1_frwr, const int* __restrict__ i0_frwr,
    const int* __restrict__ i1_frwi, const int* __restrict__ i0_frwi,
    const int* __restrict__ i1_fiwr, const int* __restrict__ i0_fiwr,
    const int* __restrict__ i1_fiwi, const int* __restrict__ i0_fiwi,
    float* __restrict__ out)
{
    __shared__ float rng_s[256];
    __shared__ int redA[4], redB[4];
    const int tid = threadIdx.x;
    rng_s[tid] = rng[tid];

    const int o = blockIdx.x;

    // x vectors (16 KB total, L2-hot): batch0 = cols [tid*4), batch1 = +1024
    const float4 xrA = *(const float4*)(input_r + tid * 4);
    const float4 xiA = *(const float4*)(input_i + tid * 4);
    const float4 xrB = *(const float4*)(input_r + 1024 + tid * 4);
    const float4 xiB = *(const float4*)(input_i + 1024 + tid * 4);

    __syncthreads();   // rng_s visible; drains ALL prior vmem (vmcnt=0 here)

    const bool xr[8] = { xrA.x > 0.5f, xrA.y > 0.5f, xrA.z > 0.5f, xrA.w > 0.5f,
                         xrB.x > 0.5f, xrB.y > 0.5f, xrB.z > 0.5f, xrB.w > 0.5f };
    const bool xi[8] = { xiA.x > 0.5f, xiA.y > 0.5f, xiA.z > 0.5f, xiA.w > 0.5f,
                         xiB.x > 0.5f, xiB.y > 0.5f, xiB.z > 0.5f, xiB.w > 0.5f };

    const unsigned v0 = (unsigned)o * 8192u + (unsigned)tid * 16u;  // row*2048*4 + col*4
    const unsigned v1 = v0 + 4096u;                                 // +1024 cols

    int4v sr0, si0, a1_0, a0_0, b1_0, b0_0, c1_0, c0_0, d1_0, d0_0;
    int4v sr1, si1, a1_1, a0_1, b1_1, b0_1, c1_1, c0_1, d1_1, d0_1;

    // ---- issue all 20 loads back-to-back (1.28 KB/wave in flight) ----
    GLOAD(sr0, src_r,   v0);  GLOAD(si0, src_i,   v0);
    GLOAD(a1_0, i1_frwr, v0); GLOAD(a0_0, i0_frwr, v0);
    GLOAD(b1_0, i1_frwi, v0); GLOAD(b0_0, i0_frwi, v0);
    GLOAD(c1_0, i1_fiwr, v0); GLOAD(c0_0, i0_fiwr, v0);
    GLOAD(d1_0, i1_fiwi, v0); GLOAD(d0_0, i0_fiwi, v0);
    GLOAD(sr1, src_r,   v1);  GLOAD(si1, src_i,   v1);
    GLOAD(a1_1, i1_frwr, v1); GLOAD(a0_1, i0_frwr, v1);
    GLOAD(b1_1, i1_frwi, v1); GLOAD(b0_1, i0_frwi, v1);
    GLOAD(c1_1, i1_fiwr, v1); GLOAD(c0_1, i0_fiwr, v1);
    GLOAD(d1_1, i1_fiwi, v1); GLOAD(d0_1, i0_fiwi, v1);

    int accA = 0, accB = 0;

    // bit = (src > rng[x ? idx1 : idx0]) == x ; fiwi uses x = 1-xi
    #define ELEM(k, q, xq)                                                   \
    {                                                                        \
        const float sr = __int_as_float(sr##k[q]);                           \
        const float si = __int_as_float(si##k[q]);                           \
        const bool xr_ = xr[xq], xi_ = xi[xq];                               \
        const int ia = (xr_ ? a1_##k[q] : a0_##k[q]) & 255;                  \
        const int ib = (xr_ ? b1_##k[q] : b0_##k[q]) & 255;                  \
        const int ic = (xi_ ? c1_##k[q] : c0_##k[q]) & 255;                  \
        const int id = (xi_ ? d0_##k[q] : d1_##k[q]) & 255;                  \
        const bool cA = sr > rng_s[ia];                                      \
        const bool cB = si > rng_s[ib];                                      \
        const bool cC = sr > rng_s[ic];                                      \
        const bool cD = si > rng_s[id];                                      \
        accA += (int)(cA == xr_) + (int)(cD != xi_);                         \
        accB += (int)(cB == xr_) + (int)(cC == xi_);                         \
    }

    asm volatile("s_waitcnt vmcnt(10)" ::: "memory");  // drain batch 0 only
    __builtin_amdgcn_sched_barrier(0);
    ELEM(0, 0, 0) ELEM(0, 1, 1) ELEM(0, 2, 2) ELEM(0, 3, 3)

    asm volatile("s_waitcnt vmcnt(0)" ::: "memory");   // drain batch 1
    __builtin_amdgcn_sched_barrier(0);
    ELEM(1, 0, 4) ELEM(1, 1, 5) ELEM(1, 2, 6) ELEM(1, 3, 7)
    #undef ELEM

    // ---- wave (64-lane) reduction, then cross-wave via LDS ----
    #pragma unroll
    for (int off = 32; off > 0; off >>= 1) {
        accA += __shfl_down(accA, off);
        accB += __shfl_down(accB, off);
    }
    const int wid = tid >> 6;
    if ((tid & 63) == 0) { redA[wid] = accA; redB[wid] = accB; }
    __syncthreads();
    if (tid == 0) {
        const int sA = redA[0] + redA[1] + redA[2] + redA[3];
        const int sB = redB[0] + redB[1] + redB[2] + redB[3];
        out[o]           = (sA >= 2048) ? 1.0f : 0.0f;   // acc - 2047.5 > 0
        out[OUT_DIM + o] = (sB >= 2048) ? 1.0f : 0.0f;
    }
}

extern "C" void kernel_launch(void* const* d_in, const int* in_sizes, int n_in,
                              void* d_out, int out_size, void* d_ws, size_t ws_size,
                              hipStream_t stream) {
    const float* input_r = (const float*)d_in[0];
    const float* input_i = (const float*)d_in[1];
    const float* src_r   = (const float*)d_in[2];
    const float* src_i   = (const float*)d_in[3];
    const float* rng     = (const float*)d_in[4];
    const int* i1_frwr = (const int*)d_in[5];
    const int* i0_frwr = (const int*)d_in[6];
    const int* i1_frwi = (const int*)d_in[7];
    const int* i0_frwi = (const int*)d_in[8];
    const int* i1_fiwr = (const int*)d_in[9];
    const int* i0_fiwr = (const int*)d_in[10];
    const int* i1_fiwi = (const int*)d_in[11];
    const int* i0_fiwi = (const int*)d_in[12];
    float* out = (float*)d_out;

    ulc_kernel<<<dim3(OUT_DIM), dim3(256), 0, stream>>>(
        input_r, input_i, src_r, src_i, rng,
        i1_frwr, i0_frwr, i1_frwi, i0_frwi,
        i1_fiwr, i0_fiwr, i1_fiwi, i0_fiwi,
        out);
}